// Round 17
// baseline (102.347 us; speedup 1.0000x reference)
//
#include <hip/hip_runtime.h>

#define NROWS 8192
#define DDIM 256
#define BT 128
#define BK 64
#define GT (NROWS / BT)            // 64 tile-rows
#define NBT (GT * (GT + 1) / 2)    // 2080 upper-triangle blocks
#define NXCD 8
#define CPX (NBT / NXCD)           // 260 blocks per XCD chunk (2080 % 8 == 0)

using bf16x8 = __attribute__((ext_vector_type(8))) __bf16;
using f32x4  = __attribute__((ext_vector_type(4))) float;

__device__ __forceinline__ void glds16(const unsigned short* g, unsigned short* l) {
    // async global->LDS DMA, 16B/lane; LDS dest = wave-uniform base + lane*16
    __builtin_amdgcn_global_load_lds(
        (const __attribute__((address_space(1))) unsigned int*)g,
        (__attribute__((address_space(3))) unsigned int*)l,
        16, 0, 0);
}

__device__ __forceinline__ unsigned short f2bf(float f) {
    unsigned int b = __float_as_uint(f);
    unsigned int r = b + 0x7fffu + ((b >> 16) & 1u);
    return (unsigned short)(r >> 16);
}

// Kernel 1: one wave per row. Normalize, CENTER (e - mean), emit bf16 e~,
// and per-row epilogue constants:
//   dist_ij = (b_i + b_j - (e~_i . e~_j)/128) / b_i
//   v_neg(i,j) = 0.2 - dist_ij = fmaf(aP_i, raw + bs_j, -0.8),  raw = MFMA acc
//   v_pos(i,j) = dist_ij - 0.01 = 0.19 - v_neg(i,j)
//   with aP = (1/b)/128, bs = -128*b  (aP*bs = -1 exactly -> constant -0.8)
__global__ __launch_bounds__(256) void rowstats_kernel(
    const float* __restrict__ x, unsigned short* __restrict__ ebf,
    float* __restrict__ aP, float* __restrict__ bs,
    float* __restrict__ rabs)
{
    int wave = threadIdx.x >> 6;
    int lane = threadIdx.x & 63;
    int row  = blockIdx.x * 4 + wave;

    const float4 v = reinterpret_cast<const float4*>(x + (size_t)row * DDIM)[lane];
    float ss = v.x * v.x + v.y * v.y + v.z * v.z + v.w * v.w;
    float sm = v.x + v.y + v.z + v.w;
    #pragma unroll
    for (int off = 32; off >= 1; off >>= 1) {
        ss += __shfl_xor(ss, off);
        sm += __shfl_xor(sm, off);
    }
    float invn = 1.0f / sqrtf(ss);
    float m = sm * invn * (1.0f / DDIM);

    ushort4 o;
    o.x = f2bf(v.x * invn - m);
    o.y = f2bf(v.y * invn - m);
    o.z = f2bf(v.z * invn - m);
    o.w = f2bf(v.w * invn - m);
    reinterpret_cast<ushort4*>(ebf + (size_t)row * DDIM)[lane] = o;

    if (lane == 0) {
        float s  = ss * invn * invn * (1.0f / DDIM);
        float b  = s - m * m;
        float a  = 1.0f / b;
        aP[row]   = a * (1.0f / 128.0f);
        bs[row]   = -128.0f * b;
        rabs[row] = fabsf(sm * invn);
    }
}

// Kernel 2: upper-triangle E~.E~^T bf16 MFMA GEMM, 128x128 tiles, BK=64.
// Round-16 confirmed the traffic theory (BT 64->128 halved staging, -11us).
// Round-17: XCD-AWARE CHUNKED SWIZZLE (T1). Staging runs at 8.2 TB/s with
// FETCH only ~18MB -> L3-bound because per-XCD L2 (4MB ~= ebf) thrashes
// under the default round-robin t->XCD mapping (each XCD's ~128 concurrent
// blocks span all tile-rows). Chunked remap t -> (t%8)*260 + t/8 gives each
// XCD a contiguous t-range: concurrent blocks share ~2-5 A-tiles (L2-
// resident) and consecutive B-tiles. 2080 % 8 == 0 -> bijective.
__global__ __launch_bounds__(256) void snr_gemm_kernel(
    const unsigned short* __restrict__ ebf,
    const float* __restrict__ aP, const float* __restrict__ bs,
    const int* __restrict__ labels,
    float* __restrict__ partials)
{
    __shared__ __align__(16) unsigned short As[BT * BK];   // 16 KB, swizzled chunks
    __shared__ __align__(16) unsigned short Bs[BT * BK];   // 16 KB
    __shared__ float sAPi[BT], sBsi[BT];
    __shared__ float sAPj[BT], sBsj[BT];
    __shared__ int   sLi[BT], sLj[BT];
    __shared__ float redbuf[4][4];

    int tid  = threadIdx.x;
    int lane = tid & 63;
    int wave = tid >> 6;
    int wr = (wave >> 1) * 64;
    int wc = (wave & 1) * 64;

    // XCD-aware chunked swizzle (bijective since NBT % NXCD == 0)
    int t = (blockIdx.x % NXCD) * CPX + blockIdx.x / NXCD;

    // decode triangular block id -> (bi, bj), bi <= bj
    int bi = (int)((2.0f * GT + 1.0f
                    - sqrtf((2.0f * GT + 1.0f) * (2.0f * GT + 1.0f) - 8.0f * (float)t)) * 0.5f);
    while ((bi + 1) * GT - ((bi + 1) * bi) / 2 <= t) ++bi;
    while (bi * GT - (bi * (bi - 1)) / 2 > t) --bi;
    int bj = bi + (t - (bi * GT - (bi * (bi - 1)) / 2));
    int rowBase = bi * BT, colBase = bj * BT;
    bool diag = (bi == bj);

    // stage per-row / per-col epilogue constants (covered by first K-loop barrier)
    if (tid < BT) {
        int gi = rowBase + tid;
        sAPi[tid] = aP[gi]; sBsi[tid] = bs[gi];
        sLi[tid] = labels[gi];
    } else {
        int tt = tid - BT;
        int gj = colBase + tt;
        sAPj[tt] = aP[gj]; sBsj[tt] = bs[gj];
        sLj[tt] = labels[gj];
    }

    // staging addresses: chunk q = p*256+tid; logical (row=q>>3, slot=q&7),
    // slot holds k-chunk kc = slot ^ (row&7)  (XOR swizzle, conflict-free)
    const unsigned short* gA[4];
    const unsigned short* gB[4];
    unsigned short* lpA[4];
    unsigned short* lpB[4];
    #pragma unroll
    for (int p = 0; p < 4; ++p) {
        int q   = p * 256 + tid;
        int row = q >> 3;
        int kc  = (q & 7) ^ (row & 7);
        gA[p] = ebf + (size_t)(rowBase + row) * DDIM + kc * 8;
        gB[p] = ebf + (size_t)(colBase + row) * DDIM + kc * 8;
        lpA[p] = As + q * 8;
        lpB[p] = Bs + q * 8;
    }

    // fragment LDS offsets (elems), swizzle-aware
    int mrow = lane & 15;
    int kch  = lane >> 4;          // 16B k-chunk within half
    int offA[4][2], offB[4][2];
    #pragma unroll
    for (int t4 = 0; t4 < 4; ++t4) {
        int rA = wr + t4 * 16 + mrow;
        int rB = wc + t4 * 16 + mrow;
        #pragma unroll
        for (int h = 0; h < 2; ++h) {
            offA[t4][h] = (rA * 8 + ((h * 4 + kch) ^ (rA & 7))) * 8;
            offB[t4][h] = (rB * 8 + ((h * 4 + kch) ^ (rB & 7))) * 8;
        }
    }

    f32x4 acc[4][4];
    #pragma unroll
    for (int a = 0; a < 4; ++a)
        #pragma unroll
        for (int b = 0; b < 4; ++b)
            acc[a][b] = (f32x4){0.f, 0.f, 0.f, 0.f};

    for (int it = 0; it < 4; ++it) {
        #pragma unroll
        for (int p = 0; p < 4; ++p) {
            glds16(gA[p], lpA[p]);
            glds16(gB[p], lpB[p]);
            gA[p] += BK;
            gB[p] += BK;
        }
        asm volatile("s_waitcnt vmcnt(0)" ::: "memory");
        __syncthreads();

        #pragma unroll
        for (int h = 0; h < 2; ++h) {
            bf16x8 aF[4], bF[4];
            #pragma unroll
            for (int t4 = 0; t4 < 4; ++t4) {
                aF[t4] = *reinterpret_cast<const bf16x8*>(As + offA[t4][h]);
                bF[t4] = *reinterpret_cast<const bf16x8*>(Bs + offB[t4][h]);
            }
            #pragma unroll
            for (int ti = 0; ti < 4; ++ti)
                #pragma unroll
                for (int tj = 0; tj < 4; ++tj)
                    acc[ti][tj] = __builtin_amdgcn_mfma_f32_16x16x32_bf16(aF[ti], bF[tj], acc[ti][tj], 0, 0, 0);
        }
        __syncthreads();
    }

    // ---------------- epilogue with wave-uniform rare-site skip ----------------
    // fast path = 2 fma + 3 ballots per site; guarded work only when some lane
    // has a firing neg hinge or a same-label pair (bit-exact: skipped sites
    // contribute exactly 0 to every accumulator).
    int subr = (lane >> 4) * 4;
    int cj   = lane & 15;

    float aPC[4], bsC[4];
    int LCj[4];
    #pragma unroll
    for (int tj = 0; tj < 4; ++tj) {
        int lj = wc + tj * 16 + cj;
        aPC[tj] = sAPj[lj]; bsC[tj] = sBsj[lj];
        LCj[tj] = sLj[lj];
    }

    float Sn = 0.f, Sp = 0.f;
    unsigned Cn = 0u, Cp = 0u;   // wave-uniform (ballot/popc) -> SGPR accumulators

    if (!diag) {
        #pragma unroll
        for (int ti = 0; ti < 4; ++ti) {
            #pragma unroll
            for (int r = 0; r < 4; ++r) {
                int li = wr + ti * 16 + subr + r;
                float aR = sAPi[li], bR = sBsi[li];
                int LR = sLi[li];
                #pragma unroll
                for (int tj = 0; tj < 4; ++tj) {
                    float raw = acc[ti][tj][r];
                    float v1 = fmaf(aR, raw + bsC[tj], -0.8f);       // v_neg (i,j)
                    float v2 = fmaf(aPC[tj], raw + bR, -0.8f);       // v_neg (j,i)
                    bool same = (LR == LCj[tj]);
                    unsigned long long b1 = __ballot(v1 > 0.f);
                    unsigned long long b2 = __ballot(v2 > 0.f);
                    unsigned long long ms = __ballot(same);
                    if (b1 | b2 | ms) {                              // rare (~12% of sites)
                        float nz = fmaxf(v1, 0.f) + fmaxf(v2, 0.f);
                        Sn += same ? 0.f : nz;
                        float pz = fmaxf(0.19f - v1, 0.f) + fmaxf(0.19f - v2, 0.f);
                        Sp += same ? pz : 0.f;
                        Cn += (unsigned)__popcll(b1 & ~ms)
                            + (unsigned)__popcll(b2 & ~ms);
                        Cp += (unsigned)__popcll(__ballot(v1 < 0.19f) & ms)
                            + (unsigned)__popcll(__ballot(v2 < 0.19f) & ms);
                    }
                }
            }
        }
    } else {
        #pragma unroll
        for (int ti = 0; ti < 4; ++ti) {
            #pragma unroll
            for (int r = 0; r < 4; ++r) {
                int li = wr + ti * 16 + subr + r;
                float aR = sAPi[li];
                int LR = sLi[li];
                #pragma unroll
                for (int tj = 0; tj < 4; ++tj) {
                    int lj = wc + tj * 16 + cj;
                    float raw = acc[ti][tj][r];
                    float v1 = fmaf(aR, raw + bsC[tj], -0.8f);
                    bool same = (LR == LCj[tj]);                 // includes self
                    bool pok  = same && (li != lj);              // eye excluded from pos
                    unsigned long long b1 = __ballot(v1 > 0.f);
                    unsigned long long ms = __ballot(same);
                    if (b1 | ms) {
                        unsigned long long mp = __ballot(pok);
                        Sn += same ? 0.f : fmaxf(v1, 0.f);
                        float pz = fmaxf(0.19f - v1, 0.f);
                        Sp += pok ? pz : 0.f;
                        Cn += (unsigned)__popcll(b1 & ~ms);
                        Cp += (unsigned)__popcll(__ballot(v1 < 0.19f) & mp);
                    }
                }
            }
        }
    }

    // block reduction: Sn/Sp via shuffles; Cn/Cp already wave-uniform
    #pragma unroll
    for (int off = 32; off >= 1; off >>= 1) {
        Sn += __shfl_down(Sn, off);
        Sp += __shfl_down(Sp, off);
    }
    if (lane == 0) {
        redbuf[wave][0] = Sn; redbuf[wave][1] = (float)Cn;
        redbuf[wave][2] = Sp; redbuf[wave][3] = (float)Cp;
    }
    __syncthreads();
    if (tid < 4) {
        partials[blockIdx.x * 4 + tid] =
            redbuf[0][tid] + redbuf[1][tid] + redbuf[2][tid] + redbuf[3][tid];
    }
}

// Kernel 3: reduce per-block partials + per-row reg terms, emit scalar loss.
// Guard: if a count sums to exactly 0, the true masked sum is 0 too
// (reference yields 0/1e-12 = 0) -> emit 0 instead of residual/1e-12.
__global__ __launch_bounds__(256) void finalize_kernel(
    const float* __restrict__ partials, const float* __restrict__ rabs,
    float* __restrict__ out)
{
    int tid = threadIdx.x;
    float s0 = 0, s1 = 0, s2 = 0, s3 = 0, rr = 0;
    for (int i = tid; i < NBT; i += 256) {
        float4 p = reinterpret_cast<const float4*>(partials)[i];
        s0 += p.x; s1 += p.y; s2 += p.z; s3 += p.w;
    }
    for (int i = tid; i < NROWS; i += 256) rr += rabs[i];

    #pragma unroll
    for (int off = 32; off >= 1; off >>= 1) {
        s0 += __shfl_down(s0, off);
        s1 += __shfl_down(s1, off);
        s2 += __shfl_down(s2, off);
        s3 += __shfl_down(s3, off);
        rr += __shfl_down(rr, off);
    }
    __shared__ float red[4][5];
    int wave = tid >> 6, lane = tid & 63;
    if (lane == 0) {
        red[wave][0] = s0; red[wave][1] = s1; red[wave][2] = s2;
        red[wave][3] = s3; red[wave][4] = rr;
    }
    __syncthreads();
    if (tid == 0) {
        float a0 = 0, a1 = 0, a2 = 0, a3 = 0, a4 = 0;
        #pragma unroll
        for (int w = 0; w < 4; ++w) {
            a0 += red[w][0]; a1 += red[w][1]; a2 += red[w][2];
            a3 += red[w][3]; a4 += red[w][4];
        }
        float neg = (a1 > 0.5f) ? a0 / (a1 + 1e-12f) : 0.0f;
        float pos = (a3 > 0.5f) ? a2 / (a3 + 1e-12f) : 0.0f;
        out[0] = pos + neg + a4 * (0.1f / (float)NROWS);
    }
}

extern "C" void kernel_launch(void* const* d_in, const int* in_sizes, int n_in,
                              void* d_out, int out_size, void* d_ws, size_t ws_size,
                              hipStream_t stream) {
    const float* embeds = (const float*)d_in[0];
    const int*   labels = (const int*)d_in[1];
    float* out = (float*)d_out;

    char* ws = (char*)d_ws;
    unsigned short* ebf = (unsigned short*)ws;              // 4 MB
    float* aP   = (float*)(ws + (size_t)NROWS * DDIM * 2);
    float* bs   = aP + NROWS;
    float* rabs = bs + NROWS;
    float* partials = rabs + NROWS;                         // NBT*4 floats

    rowstats_kernel<<<NROWS / 4, 256, 0, stream>>>(embeds, ebf, aP, bs, rabs);

    snr_gemm_kernel<<<NBT, 256, 0, stream>>>(ebf, aP, bs, labels, partials);

    finalize_kernel<<<1, 256, 0, stream>>>(partials, rabs, out);
}